// Round 7
// baseline (146.154 us; speedup 1.0000x reference)
//
#include <hip/hip_runtime.h>
#include <hip/hip_bf16.h>
#include <stdint.h>
#include <stddef.h>

#define B_ 2
#define T_ 2048
#define C_ 1024
#define H_ 16
#define D_ 64
#define M_ (B_*T_)   // 4096

typedef __attribute__((ext_vector_type(8))) short short8;
typedef __attribute__((ext_vector_type(4))) float f32x4;
typedef __attribute__((ext_vector_type(16))) float f32x16;
typedef __attribute__((ext_vector_type(4))) unsigned int u32x4;

__device__ __forceinline__ unsigned short f2bf(float f) {
    unsigned u = __float_as_uint(f);
    unsigned r = 0x7FFFu + ((u >> 16) & 1u);
    return (unsigned short)((u + r) >> 16);
}

__device__ __forceinline__ unsigned cvtpk_bf16(float lo, float hi) {
    unsigned r;
    asm("v_cvt_pk_bf16_f32 %0, %1, %2" : "=v"(r) : "v"(lo), "v"(hi));
    return r;
}

// guaranteed single-instruction 2^x
__device__ __forceinline__ float fexp2(float x) {
    float r;
    asm("v_exp_f32 %0, %1" : "=v"(r) : "v"(x));
    return r;
}

// v_permlane32_swap_b32: a = [a_lo | b_lo], b = [a_hi | b_hi]
__device__ __forceinline__ void plswap(unsigned &a, unsigned &b) {
    asm("v_permlane32_swap_b32 %0, %1" : "+v"(a), "+v"(b));
}

__device__ __forceinline__ float xhalf_max(float v) {
    float a = v, b = v;
    asm("" : "+v"(b));
    asm("v_permlane32_swap_b32 %0, %1" : "+v"(a), "+v"(b));
    return fmaxf(a, b);
}
__device__ __forceinline__ float xhalf_sum(float v) {
    float a = v, b = v;
    asm("" : "+v"(b));
    asm("v_permlane32_swap_b32 %0, %1" : "+v"(a), "+v"(b));
    return a + b;
}

__device__ __forceinline__ void gload16(const void* g, void* l) {
    __builtin_amdgcn_global_load_lds(
        (__attribute__((address_space(1))) void*)g,
        (__attribute__((address_space(3))) void*)l,
        16, 0, 0);
}

// ---------------- fp32 -> bf16 conversion ----------------
__global__ void cvt_bf16(const float* __restrict__ in,
                         unsigned short* __restrict__ out, int n) {
    int idx = (blockIdx.x * blockDim.x + threadIdx.x) * 4;
    if (idx >= n) return;
    float4 v = *reinterpret_cast<const float4*>(in + idx);
    ushort4 o;
    o.x = f2bf(v.x); o.y = f2bf(v.y); o.z = f2bf(v.z); o.w = f2bf(v.w);
    *reinterpret_cast<ushort4*>(out + idx) = o;
}

__global__ void cvt_bf16_w4(const float* __restrict__ a, const float* __restrict__ b,
                            const float* __restrict__ c, const float* __restrict__ d,
                            unsigned short* __restrict__ oa, unsigned short* __restrict__ ob,
                            unsigned short* __restrict__ oc, unsigned short* __restrict__ od,
                            int n) {
    int idx = (blockIdx.x * blockDim.x + threadIdx.x) * 4;
    if (idx >= n) return;
    const float* in = (blockIdx.y == 0) ? a : (blockIdx.y == 1) ? b : (blockIdx.y == 2) ? c : d;
    unsigned short* out = (blockIdx.y == 0) ? oa : (blockIdx.y == 1) ? ob : (blockIdx.y == 2) ? oc : od;
    float4 v = *reinterpret_cast<const float4*>(in + idx);
    ushort4 o;
    o.x = f2bf(v.x); o.y = f2bf(v.y); o.z = f2bf(v.z); o.w = f2bf(v.w);
    *reinterpret_cast<ushort4*>(out + idx) = o;
}

// ---------------- fused QKV projection GEMM ----------------
// which 0 -> K [B,H,T,D], which 1 -> Q*scale [B,H,T,D], which 2 -> V^T [B,H,D,T]
__global__ __launch_bounds__(256) void gemm_qkv(
    const unsigned short* __restrict__ A,
    const unsigned short* __restrict__ W0,
    const unsigned short* __restrict__ W1,
    const unsigned short* __restrict__ W2,
    const float* __restrict__ b0,
    const float* __restrict__ b1,
    const float* __restrict__ b2,
    unsigned short* __restrict__ o0,   // k
    unsigned short* __restrict__ o1,   // q (pre-scaled by LOG2E/32)
    unsigned short* __restrict__ o2)   // vt
{
    __shared__ unsigned short As[128*32];
    __shared__ unsigned short Bs[128*32];
    int which = blockIdx.x >> 8;
    int bx = blockIdx.x & 255;
    int bm = bx >> 3, bn = bx & 7;
    const unsigned short* W = (which==0) ? W0 : ((which==1) ? W1 : W2);
    const float* bias = (which==0) ? b0 : ((which==1) ? b1 : b2);

    int tid = threadIdx.x;
    int lane = tid & 63;
    int fr = lane & 15, fq = lane >> 4;
    int wid = tid >> 6;
    int wr = wid >> 1, wc = wid & 1;

    int srow = tid >> 2;            // 0..63
    int scol = (tid & 3) << 3;      // 0,8,16,24
    const unsigned short* Ab = A + (size_t)(bm*128 + srow) * C_ + scol;
    const unsigned short* Wb = W + (size_t)(bn*128 + srow) * C_ + scol;

    f32x4 acc[4][4] = {};

    for (int kt = 0; kt < C_/32; ++kt) {
        int ko = kt*32;
        gload16(Ab + ko,            &As[tid*8]);
        gload16(Ab + 64*C_ + ko,    &As[2048 + tid*8]);
        gload16(Wb + ko,            &Bs[tid*8]);
        gload16(Wb + 64*C_ + ko,    &Bs[2048 + tid*8]);
        __syncthreads();
        short8 af[4], bfr[4];
        #pragma unroll
        for (int i = 0; i < 4; ++i) {
            af[i]  = *reinterpret_cast<const short8*>(&As[(wr*64 + i*16 + fr)*32 + fq*8]);
            bfr[i] = *reinterpret_cast<const short8*>(&Bs[(wc*64 + i*16 + fr)*32 + fq*8]);
        }
        #pragma unroll
        for (int i = 0; i < 4; ++i)
            #pragma unroll
            for (int j = 0; j < 4; ++j)
                acc[i][j] = __builtin_amdgcn_mfma_f32_16x16x32_bf16(af[i], bfr[j], acc[i][j], 0, 0, 0);
        __syncthreads();
    }

    // Q: fold 1/sqrt(C)=1/32 AND log2(e) so QK^T lands in log2 domain
    float sc = (which == 1) ? 0.045084220f : 1.0f;
    int mbase = bm*128 + wr*64;
    int nbase = bn*128 + wc*64;
    #pragma unroll
    for (int j = 0; j < 4; ++j) {
        int col = nbase + j*16 + fr;
        float bv = bias[col];
        int h = col >> 6, d = col & 63;
        #pragma unroll
        for (int i = 0; i < 4; ++i) {
            int r0 = mbase + i*16 + fq*4;
            #pragma unroll
            for (int r = 0; r < 4; ++r) {
                float v = (acc[i][j][r] + bv) * sc;
                int m = r0 + r;
                int b = m >> 11, t = m & (T_-1);
                unsigned short hv = f2bf(v);
                if (which == 2)
                    o2[((size_t)(b*H_ + h)*D_ + d)*T_ + t] = hv;
                else {
                    unsigned short* o = (which==0) ? o0 : o1;
                    o[((size_t)(b*H_ + h)*T_ + t)*D_ + d] = hv;
                }
            }
        }
    }
}

// ---------------- output projection GEMM ----------------
__global__ __launch_bounds__(256) void gemm_out(
    const unsigned short* __restrict__ A,   // y bf16 [M_][C_]
    const unsigned short* __restrict__ W,   // Wo bf16 [C_][C_]
    const float* __restrict__ bias,
    float* __restrict__ out)
{
    __shared__ unsigned short As[128*32];
    __shared__ unsigned short Bs[128*32];
    int bx = blockIdx.x;
    int bm = bx >> 3, bn = bx & 7;

    int tid = threadIdx.x;
    int lane = tid & 63;
    int fr = lane & 15, fq = lane >> 4;
    int wid = tid >> 6;
    int wr = wid >> 1, wc = wid & 1;

    int srow = tid >> 2;
    int scol = (tid & 3) << 3;
    const unsigned short* Ab = A + (size_t)(bm*128 + srow) * C_ + scol;
    const unsigned short* Wb = W + (size_t)(bn*128 + srow) * C_ + scol;

    f32x4 acc[4][4] = {};

    for (int kt = 0; kt < C_/32; ++kt) {
        int ko = kt*32;
        gload16(Ab + ko,            &As[tid*8]);
        gload16(Ab + 64*C_ + ko,    &As[2048 + tid*8]);
        gload16(Wb + ko,            &Bs[tid*8]);
        gload16(Wb + 64*C_ + ko,    &Bs[2048 + tid*8]);
        __syncthreads();
        short8 af[4], bfr[4];
        #pragma unroll
        for (int i = 0; i < 4; ++i) {
            af[i]  = *reinterpret_cast<const short8*>(&As[(wr*64 + i*16 + fr)*32 + fq*8]);
            bfr[i] = *reinterpret_cast<const short8*>(&Bs[(wc*64 + i*16 + fr)*32 + fq*8]);
        }
        #pragma unroll
        for (int i = 0; i < 4; ++i)
            #pragma unroll
            for (int j = 0; j < 4; ++j)
                acc[i][j] = __builtin_amdgcn_mfma_f32_16x16x32_bf16(af[i], bfr[j], acc[i][j], 0, 0, 0);
        __syncthreads();
    }

    int mbase = bm*128 + wr*64;
    int nbase = bn*128 + wc*64;
    #pragma unroll
    for (int j = 0; j < 4; ++j) {
        int col = nbase + j*16 + fr;
        float bv = bias[col];
        #pragma unroll
        for (int i = 0; i < 4; ++i) {
            int r0 = mbase + i*16 + fq*4;
            #pragma unroll
            for (int r = 0; r < 4; ++r)
                out[(size_t)(r0 + r)*C_ + col] = acc[i][j][r] + bv;
        }
    }
}

// ---------------- flash attention (causal), swapped-QK^T 32x32 ----------------
// Deep-prefetch version: K AND V double-buffered in registers one tile ahead.
// V layout: vcur[0..1] = d-row l31 (kv slices 0,1); vcur[2..3] = d-row 32+l31.
__device__ __forceinline__ void attn_tile(
    const unsigned short* __restrict__ kNext,   // K frag base for tile ti+1
    const unsigned short* __restrict__ vNext,   // V frag base for tile ti+1
    bool isLast, int l31, int hi,
    const short8 (&qf)[4],
    const short8 (&kcur)[4], short8 (&knxt)[4],
    const short8 (&vcur)[4], short8 (&vnxt)[4],
    f32x16& o0, f32x16& o1, float& m_, float& l_)
{
    // prefetch next tile's K and V fragments (fly during this tile's body)
    knxt[0] = *reinterpret_cast<const short8*>(kNext);
    knxt[1] = *reinterpret_cast<const short8*>(kNext + 16);
    knxt[2] = *reinterpret_cast<const short8*>(kNext + 32);
    knxt[3] = *reinterpret_cast<const short8*>(kNext + 48);
    vnxt[0] = *reinterpret_cast<const short8*>(vNext);
    vnxt[1] = *reinterpret_cast<const short8*>(vNext + 16);
    vnxt[2] = *reinterpret_cast<const short8*>(vNext + 32*T_);
    vnxt[3] = *reinterpret_cast<const short8*>(vNext + 32*T_ + 16);

    // QK^T (swapped: A=K, B=Q): a0 col = q row (l31), row = kv_local
    f32x16 a0 = {};
    __builtin_amdgcn_s_setprio(1);
    a0 = __builtin_amdgcn_mfma_f32_32x32x16_bf16(kcur[0], qf[0], a0, 0, 0, 0);
    a0 = __builtin_amdgcn_mfma_f32_32x32x16_bf16(kcur[1], qf[1], a0, 0, 0, 0);
    a0 = __builtin_amdgcn_mfma_f32_32x32x16_bf16(kcur[2], qf[2], a0, 0, 0, 0);
    a0 = __builtin_amdgcn_mfma_f32_32x32x16_bf16(kcur[3], qf[3], a0, 0, 0, 0);
    __builtin_amdgcn_s_setprio(0);

    // causal mask: only the diagonal tile needs it
    if (isLast) {
        #pragma unroll
        for (int r = 0; r < 16; ++r) {
            int kvl = (r&3) + 8*(r>>2) + 4*hi;
            if (kvl > l31) a0[r] = -1e30f;
        }
    }

    // row max: pairwise tree + cross-half swap
    float x0 = fmaxf(a0[0], a0[1]),   x1 = fmaxf(a0[2], a0[3]);
    float x2 = fmaxf(a0[4], a0[5]),   x3 = fmaxf(a0[6], a0[7]);
    float x4 = fmaxf(a0[8], a0[9]),   x5 = fmaxf(a0[10], a0[11]);
    float x6 = fmaxf(a0[12], a0[13]), x7 = fmaxf(a0[14], a0[15]);
    float y0 = fmaxf(x0, x1), y1 = fmaxf(x2, x3), y2 = fmaxf(x4, x5), y3 = fmaxf(x6, x7);
    float pm = fmaxf(fmaxf(y0, y1), fmaxf(y2, y3));
    pm = xhalf_max(pm);

    // defer-max (T13)
    if (!__all(pm - m_ <= 8.0f)) {
        float mn = fmaxf(m_, pm);
        float alpha = fexp2(m_ - mn);
        l_ *= alpha;
        m_ = mn;
        #pragma unroll
        for (int r = 0; r < 16; ++r) {
            int row = (r&3) + 8*(r>>2) + 4*hi;
            float ar = __shfl(alpha, row);
            o0[r] *= ar;
            o1[r] *= ar;
        }
    }

    // P = exp2(s - m); row sum via pairwise tree + cross-half swap
    #pragma unroll
    for (int r = 0; r < 16; ++r)
        a0[r] = fexp2(a0[r] - m_);
    float s0 = a0[0]+a0[1],  s1 = a0[2]+a0[3],  s2 = a0[4]+a0[5],   s3 = a0[6]+a0[7];
    float s4 = a0[8]+a0[9],  s5 = a0[10]+a0[11], s6 = a0[12]+a0[13], s7 = a0[14]+a0[15];
    float u0 = s0+s1, u1 = s2+s3, u2 = s4+s5, u3 = s6+s7;
    float rs = (u0+u1) + (u2+u3);
    rs = xhalf_sum(rs);
    l_ += rs;

    // pack P to bf16 pairs
    unsigned pk_[8];
    #pragma unroll
    for (int jj = 0; jj < 8; ++jj)
        pk_[jj] = cvtpk_bf16(a0[2*jj], a0[2*jj+1]);

    // PV: A-frag redistribution via permlane32_swap
    #pragma unroll
    for (int kb = 0; kb < 2; ++kb) {
        unsigned fx = pk_[4*kb+0], fz = pk_[4*kb+2];
        unsigned fy = pk_[4*kb+1], fw = pk_[4*kb+3];
        plswap(fx, fz);
        plswap(fy, fw);
        u32x4 wv;
        wv.x = fx; wv.y = fy; wv.z = fz; wv.w = fw;
        short8 pfrag = __builtin_bit_cast(short8, wv);
        __builtin_amdgcn_s_setprio(1);
        o0 = __builtin_amdgcn_mfma_f32_32x32x16_bf16(pfrag, vcur[kb],     o0, 0, 0, 0);
        o1 = __builtin_amdgcn_mfma_f32_32x32x16_bf16(pfrag, vcur[2 + kb], o1, 0, 0, 0);
        __builtin_amdgcn_s_setprio(0);
    }
}

__global__ __launch_bounds__(256, 2) void flash_attn(
    const unsigned short* __restrict__ q,
    const unsigned short* __restrict__ k,
    const unsigned short* __restrict__ vt,
    unsigned short* __restrict__ y)
{
    __shared__ float oP[4][32][68];   // split, q-row, d (pad 64->68) = 34 KB
    __shared__ float mP[4][32];
    __shared__ float lP[4][32];

    int tid = threadIdx.x, lane = tid & 63, s = tid >> 6;   // s = KV split 0..3
    int l31 = lane & 31, hi = lane >> 5;
    int bid = blockIdx.x;

    int xcd = bid & 7;
    int idx = bid >> 3;               // 0..127
    int bh  = xcd*4 + (idx & 3);      // 4 heads per XCD for L2 locality
    int j   = idx >> 2;               // 0..31

    const unsigned short* kp = k  + (size_t)bh*T_*D_;
    const unsigned short* vp = vt + (size_t)bh*D_*T_;
    int b = bh >> 4, h = bh & 15;

    #pragma unroll
    for (int ph = 0; ph < 2; ++ph) {
        int qblk = ph ? (63 - j) : j;
        const unsigned short* qp = q + ((size_t)bh*T_ + qblk*32) * D_;

        short8 qf[4];
        #pragma unroll
        for (int dk = 0; dk < 4; ++dk)
            qf[dk] = *reinterpret_cast<const short8*>(qp + (size_t)l31*D_ + dk*16 + hi*8);

        f32x16 o0 = {}, o1 = {};
        float m_ = -1e30f, l_ = 0.f;

        int nt = qblk + 1;
        int chunk = (nt + 3) >> 2;
        int t0 = s * chunk; if (t0 > nt) t0 = nt;
        int t1 = t0 + chunk; if (t1 > nt) t1 = nt;

        if (t0 < t1) {
            short8 kfA[4], kfB[4], vfA[4], vfB[4];
            // prologue: load tile t0's K and V fragments directly
            const unsigned short* kr = kp + (t0*32 + l31) * D_ + hi*8;
            kfA[0] = *reinterpret_cast<const short8*>(kr);
            kfA[1] = *reinterpret_cast<const short8*>(kr + 16);
            kfA[2] = *reinterpret_cast<const short8*>(kr + 32);
            kfA[3] = *reinterpret_cast<const short8*>(kr + 48);
            const unsigned short* vr = vp + l31*T_ + t0*32 + hi*8;
            vfA[0] = *reinterpret_cast<const short8*>(vr);         // d row l31,    kv slice 0
            vfA[1] = *reinterpret_cast<const short8*>(vr + 16);    // d row l31,    kv slice 1
            vfA[2] = *reinterpret_cast<const short8*>(vr + 32*T_); // d row 32+l31, kv slice 0
            vfA[3] = *reinterpret_cast<const short8*>(vr + 32*T_ + 16);

            // prefetch pointers for tile ti+1 (bounded overshoot stays in d_ws)
            const unsigned short* kpf = kr + 32*D_;
            const unsigned short* vpf = vr + 32;

            int ti = t0;
            while (ti + 2 <= t1) {
                attn_tile(kpf, vpf, ti == nt-1, l31, hi, qf, kfA, kfB, vfA, vfB, o0, o1, m_, l_);
                ++ti; kpf += 32*D_; vpf += 32;
                attn_tile(kpf, vpf, ti == nt-1, l31, hi, qf, kfB, kfA, vfB, vfA, o0, o1, m_, l_);
                ++ti; kpf += 32*D_; vpf += 32;
            }
            if (ti < t1) {
                attn_tile(kpf, vpf, ti == nt-1, l31, hi, qf, kfA, kfB, vfA, vfB, o0, o1, m_, l_);
                ++ti;
            }
        }

        // ---- store partials ----
        #pragma unroll
        for (int r = 0; r < 16; ++r) {
            int crow = (r&3) + 8*(r>>2) + 4*hi;
            oP[s][crow][l31]      = o0[r];
            oP[s][crow][32 + l31] = o1[r];
        }
        if (!hi) { mP[s][l31] = m_; lP[s][l31] = l_; }
        __syncthreads();

        // ---- 4-way merge + y write ----
        {
            int qr = tid >> 3;        // 0..31
            int dc = tid & 7;         // 0..7 (8 d each)
            float m0 = mP[0][qr], m1 = mP[1][qr], m2 = mP[2][qr], m3 = mP[3][qr];
            float ms = fmaxf(fmaxf(m0, m1), fmaxf(m2, m3));
            float a0_ = fexp2(m0 - ms), a1_ = fexp2(m1 - ms);
            float a2_ = fexp2(m2 - ms), a3_ = fexp2(m3 - ms);
            float ls = a0_*lP[0][qr] + a1_*lP[1][qr] + a2_*lP[2][qr] + a3_*lP[3][qr];
            float inv = 1.0f / ls;

            float4 v0a = *reinterpret_cast<const float4*>(&oP[0][qr][dc*8]);
            float4 v0b = *reinterpret_cast<const float4*>(&oP[0][qr][dc*8+4]);
            float4 v1a = *reinterpret_cast<const float4*>(&oP[1][qr][dc*8]);
            float4 v1b = *reinterpret_cast<const float4*>(&oP[1][qr][dc*8+4]);
            float4 v2a = *reinterpret_cast<const float4*>(&oP[2][qr][dc*8]);
            float4 v2b = *reinterpret_cast<const float4*>(&oP[2][qr][dc*8+4]);
            float4 v3a = *reinterpret_cast<const float4*>(&oP[3][qr][dc*8]);
            float4 v3b = *reinterpret_cast<const float4*>(&oP[3][qr][dc*8+4]);

            float va[8];
            va[0] = a0_*v0a.x + a1_*v1a.x + a2_*v2a.x + a3_*v3a.x;
            va[1] = a0_*v0a.y + a1_*v1a.y + a2_*v2a.y + a3_*v3a.y;
            va[2] = a0_*v0a.z + a1_*v1a.z + a2_*v2a.z + a3_*v3a.z;
            va[3] = a0_*v0a.w + a1_*v1a.w + a2_*v2a.w + a3_*v3a.w;
            va[4] = a0_*v0b.x + a1_*v1b.x + a2_*v2b.x + a3_*v3b.x;
            va[5] = a0_*v0b.y + a1_*v1b.y + a2_*v2b.y + a3_*v3b.y;
            va[6] = a0_*v0b.z + a1_*v1b.z + a2_*v2b.z + a3_*v3b.z;
            va[7] = a0_*v0b.w + a1_*v1b.w + a2_*v2b.w + a3_*v3b.w;

            unsigned short yv[8];
            #pragma unroll
            for (int e = 0; e < 8; ++e) yv[e] = f2bf(va[e] * inv);

            int trow = qblk*32 + qr;
            size_t base = ((size_t)(b*T_ + trow))*C_ + h*64 + dc*8;
            *reinterpret_cast<short8*>(y + base) = *reinterpret_cast<short8*>(yv);
        }
        __syncthreads();   // protect LDS reuse by next phase
    }
}

extern "C" void kernel_launch(void* const* d_in, const int* in_sizes, int n_in,
                              void* d_out, int out_size, void* d_ws, size_t ws_size,
                              hipStream_t stream) {
    const float* x  = (const float*)d_in[0];
    const float* Wk = (const float*)d_in[1];
    const float* bk = (const float*)d_in[2];
    const float* Wq = (const float*)d_in[3];
    const float* bq = (const float*)d_in[4];
    const float* Wv = (const float*)d_in[5];
    const float* bv = (const float*)d_in[6];
    const float* Wo = (const float*)d_in[7];
    const float* bo = (const float*)d_in[8];
    float* out = (float*)d_out;

    char* ws = (char*)d_ws;
    unsigned short* xb  = (unsigned short*)(ws);                    // 8MB
    unsigned short* wkb = (unsigned short*)(ws + ((size_t)8  << 20));
    unsigned short* wqb = (unsigned short*)(ws + ((size_t)10 << 20));
    unsigned short* wvb = (unsigned short*)(ws + ((size_t)12 << 20));
    unsigned short* wob = (unsigned short*)(ws + ((size_t)14 << 20));
    unsigned short* qb  = (unsigned short*)(ws + ((size_t)16 << 20)); // [B,H,T,D]
    unsigned short* kb  = (unsigned short*)(ws + ((size_t)24 << 20)); // [B,H,T,D]
    unsigned short* vtb = (unsigned short*)(ws + ((size_t)32 << 20)); // [B,H,D,T]
    unsigned short* yb  = (unsigned short*)(ws + ((size_t)40 << 20)); // [B*T,C]

    const int nx = B_*T_*C_;   // 4M
    const int nw = C_*C_;      // 1M

    cvt_bf16<<<dim3(nx/4/256), dim3(256), 0, stream>>>(x, xb, nx);
    cvt_bf16_w4<<<dim3(nw/4/256, 4), dim3(256), 0, stream>>>(
        Wk, Wq, Wv, Wo, wkb, wqb, wvb, wob, nw);

    gemm_qkv<<<dim3(768), dim3(256), 0, stream>>>(xb, wkb, wqb, wvb, bk, bq, bv, kb, qb, vtb);

    flash_attn<<<dim3(1024), dim3(256), 0, stream>>>(qb, kb, vtb, yb);

    gemm_out<<<dim3(256), dim3(256), 0, stream>>>(yb, wob, bo, out);
}

// Round 8
// 145.304 us; speedup vs baseline: 1.0059x; 1.0059x over previous
//
#include <hip/hip_runtime.h>
#include <hip/hip_bf16.h>
#include <stdint.h>
#include <stddef.h>

#define B_ 2
#define T_ 2048
#define C_ 1024
#define H_ 16
#define D_ 64
#define M_ (B_*T_)   // 4096

typedef __attribute__((ext_vector_type(8))) short short8;
typedef __attribute__((ext_vector_type(4))) float f32x4;
typedef __attribute__((ext_vector_type(16))) float f32x16;
typedef __attribute__((ext_vector_type(4))) unsigned int u32x4;

__device__ __forceinline__ unsigned short f2bf(float f) {
    unsigned u = __float_as_uint(f);
    unsigned r = 0x7FFFu + ((u >> 16) & 1u);
    return (unsigned short)((u + r) >> 16);
}

__device__ __forceinline__ unsigned cvtpk_bf16(float lo, float hi) {
    unsigned r;
    asm("v_cvt_pk_bf16_f32 %0, %1, %2" : "=v"(r) : "v"(lo), "v"(hi));
    return r;
}

// guaranteed single-instruction 2^x
__device__ __forceinline__ float fexp2(float x) {
    float r;
    asm("v_exp_f32 %0, %1" : "=v"(r) : "v"(x));
    return r;
}

// v_permlane32_swap_b32: a = [a_lo | b_lo], b = [a_hi | b_hi]
__device__ __forceinline__ void plswap(unsigned &a, unsigned &b) {
    asm("v_permlane32_swap_b32 %0, %1" : "+v"(a), "+v"(b));
}

__device__ __forceinline__ float xhalf_max(float v) {
    float a = v, b = v;
    asm("" : "+v"(b));
    asm("v_permlane32_swap_b32 %0, %1" : "+v"(a), "+v"(b));
    return fmaxf(a, b);
}
__device__ __forceinline__ float xhalf_sum(float v) {
    float a = v, b = v;
    asm("" : "+v"(b));
    asm("v_permlane32_swap_b32 %0, %1" : "+v"(a), "+v"(b));
    return a + b;
}

__device__ __forceinline__ void gload16(const void* g, void* l) {
    __builtin_amdgcn_global_load_lds(
        (__attribute__((address_space(1))) void*)g,
        (__attribute__((address_space(3))) void*)l,
        16, 0, 0);
}

// ---------------- fp32 -> bf16 conversion ----------------
__global__ void cvt_bf16(const float* __restrict__ in,
                         unsigned short* __restrict__ out, int n) {
    int idx = (blockIdx.x * blockDim.x + threadIdx.x) * 4;
    if (idx >= n) return;
    float4 v = *reinterpret_cast<const float4*>(in + idx);
    ushort4 o;
    o.x = f2bf(v.x); o.y = f2bf(v.y); o.z = f2bf(v.z); o.w = f2bf(v.w);
    *reinterpret_cast<ushort4*>(out + idx) = o;
}

__global__ void cvt_bf16_w4(const float* __restrict__ a, const float* __restrict__ b,
                            const float* __restrict__ c, const float* __restrict__ d,
                            unsigned short* __restrict__ oa, unsigned short* __restrict__ ob,
                            unsigned short* __restrict__ oc, unsigned short* __restrict__ od,
                            int n) {
    int idx = (blockIdx.x * blockDim.x + threadIdx.x) * 4;
    if (idx >= n) return;
    const float* in = (blockIdx.y == 0) ? a : (blockIdx.y == 1) ? b : (blockIdx.y == 2) ? c : d;
    unsigned short* out = (blockIdx.y == 0) ? oa : (blockIdx.y == 1) ? ob : (blockIdx.y == 2) ? oc : od;
    float4 v = *reinterpret_cast<const float4*>(in + idx);
    ushort4 o;
    o.x = f2bf(v.x); o.y = f2bf(v.y); o.z = f2bf(v.z); o.w = f2bf(v.w);
    *reinterpret_cast<ushort4*>(out + idx) = o;
}

// ---------------- fused QKV projection GEMM ----------------
// which 0 -> K [B,H,T,D], which 1 -> Q*scale [B,H,T,D], which 2 -> V^T [B,H,D,T]
__global__ __launch_bounds__(256) void gemm_qkv(
    const unsigned short* __restrict__ A,
    const unsigned short* __restrict__ W0,
    const unsigned short* __restrict__ W1,
    const unsigned short* __restrict__ W2,
    const float* __restrict__ b0,
    const float* __restrict__ b1,
    const float* __restrict__ b2,
    unsigned short* __restrict__ o0,   // k
    unsigned short* __restrict__ o1,   // q (pre-scaled by LOG2E/32)
    unsigned short* __restrict__ o2)   // vt
{
    __shared__ unsigned short As[128*32];
    __shared__ unsigned short Bs[128*32];
    int which = blockIdx.x >> 8;
    int bx = blockIdx.x & 255;
    int bm = bx >> 3, bn = bx & 7;
    const unsigned short* W = (which==0) ? W0 : ((which==1) ? W1 : W2);
    const float* bias = (which==0) ? b0 : ((which==1) ? b1 : b2);

    int tid = threadIdx.x;
    int lane = tid & 63;
    int fr = lane & 15, fq = lane >> 4;
    int wid = tid >> 6;
    int wr = wid >> 1, wc = wid & 1;

    int srow = tid >> 2;            // 0..63
    int scol = (tid & 3) << 3;      // 0,8,16,24
    const unsigned short* Ab = A + (size_t)(bm*128 + srow) * C_ + scol;
    const unsigned short* Wb = W + (size_t)(bn*128 + srow) * C_ + scol;

    f32x4 acc[4][4] = {};

    for (int kt = 0; kt < C_/32; ++kt) {
        int ko = kt*32;
        gload16(Ab + ko,            &As[tid*8]);
        gload16(Ab + 64*C_ + ko,    &As[2048 + tid*8]);
        gload16(Wb + ko,            &Bs[tid*8]);
        gload16(Wb + 64*C_ + ko,    &Bs[2048 + tid*8]);
        __syncthreads();
        short8 af[4], bfr[4];
        #pragma unroll
        for (int i = 0; i < 4; ++i) {
            af[i]  = *reinterpret_cast<const short8*>(&As[(wr*64 + i*16 + fr)*32 + fq*8]);
            bfr[i] = *reinterpret_cast<const short8*>(&Bs[(wc*64 + i*16 + fr)*32 + fq*8]);
        }
        #pragma unroll
        for (int i = 0; i < 4; ++i)
            #pragma unroll
            for (int j = 0; j < 4; ++j)
                acc[i][j] = __builtin_amdgcn_mfma_f32_16x16x32_bf16(af[i], bfr[j], acc[i][j], 0, 0, 0);
        __syncthreads();
    }

    // Q: fold 1/sqrt(C)=1/32 AND log2(e) so QK^T lands in log2 domain
    float sc = (which == 1) ? 0.045084220f : 1.0f;
    int mbase = bm*128 + wr*64;
    int nbase = bn*128 + wc*64;
    #pragma unroll
    for (int j = 0; j < 4; ++j) {
        int col = nbase + j*16 + fr;
        float bv = bias[col];
        int h = col >> 6, d = col & 63;
        #pragma unroll
        for (int i = 0; i < 4; ++i) {
            int r0 = mbase + i*16 + fq*4;
            #pragma unroll
            for (int r = 0; r < 4; ++r) {
                float v = (acc[i][j][r] + bv) * sc;
                int m = r0 + r;
                int b = m >> 11, t = m & (T_-1);
                unsigned short hv = f2bf(v);
                if (which == 2)
                    o2[((size_t)(b*H_ + h)*D_ + d)*T_ + t] = hv;
                else {
                    unsigned short* o = (which==0) ? o0 : o1;
                    o[((size_t)(b*H_ + h)*T_ + t)*D_ + d] = hv;
                }
            }
        }
    }
}

// ---------------- output projection GEMM ----------------
__global__ __launch_bounds__(256) void gemm_out(
    const unsigned short* __restrict__ A,   // y bf16 [M_][C_]
    const unsigned short* __restrict__ W,   // Wo bf16 [C_][C_]
    const float* __restrict__ bias,
    float* __restrict__ out)
{
    __shared__ unsigned short As[128*32];
    __shared__ unsigned short Bs[128*32];
    int bx = blockIdx.x;
    int bm = bx >> 3, bn = bx & 7;

    int tid = threadIdx.x;
    int lane = tid & 63;
    int fr = lane & 15, fq = lane >> 4;
    int wid = tid >> 6;
    int wr = wid >> 1, wc = wid & 1;

    int srow = tid >> 2;
    int scol = (tid & 3) << 3;
    const unsigned short* Ab = A + (size_t)(bm*128 + srow) * C_ + scol;
    const unsigned short* Wb = W + (size_t)(bn*128 + srow) * C_ + scol;

    f32x4 acc[4][4] = {};

    for (int kt = 0; kt < C_/32; ++kt) {
        int ko = kt*32;
        gload16(Ab + ko,            &As[tid*8]);
        gload16(Ab + 64*C_ + ko,    &As[2048 + tid*8]);
        gload16(Wb + ko,            &Bs[tid*8]);
        gload16(Wb + 64*C_ + ko,    &Bs[2048 + tid*8]);
        __syncthreads();
        short8 af[4], bfr[4];
        #pragma unroll
        for (int i = 0; i < 4; ++i) {
            af[i]  = *reinterpret_cast<const short8*>(&As[(wr*64 + i*16 + fr)*32 + fq*8]);
            bfr[i] = *reinterpret_cast<const short8*>(&Bs[(wc*64 + i*16 + fr)*32 + fq*8]);
        }
        #pragma unroll
        for (int i = 0; i < 4; ++i)
            #pragma unroll
            for (int j = 0; j < 4; ++j)
                acc[i][j] = __builtin_amdgcn_mfma_f32_16x16x32_bf16(af[i], bfr[j], acc[i][j], 0, 0, 0);
        __syncthreads();
    }

    int mbase = bm*128 + wr*64;
    int nbase = bn*128 + wc*64;
    #pragma unroll
    for (int j = 0; j < 4; ++j) {
        int col = nbase + j*16 + fr;
        float bv = bias[col];
        #pragma unroll
        for (int i = 0; i < 4; ++i) {
            int r0 = mbase + i*16 + fq*4;
            #pragma unroll
            for (int r = 0; r < 4; ++r)
                out[(size_t)(r0 + r)*C_ + col] = acc[i][j][r] + bv;
        }
    }
}

// ---------------- flash attention: block-cooperative LDS-staged ----------------
// Block = 2 waves x 64 q-rows = 128 rows. KV tiles of 64 staged to LDS
// (double-buffered, rule-#21 XOR swizzle). Softmax/PV per 32-kv sub-tile,
// numerics identical to verified R7 path. No KV-split, no merge.
__device__ __forceinline__ void attn_subtile(
    const short8 (&kf)[4], const short8 (&qf)[4],
    const short8 (&vlo)[2], const short8 (&vhi)[2],
    bool diag, int l31, int hi,
    f32x16& o0, f32x16& o1, float& m_, float& l_)
{
    // QK^T (swapped: A=K, B=Q): a0 col = q row (l31), row = kv_local
    f32x16 a0 = {};
    __builtin_amdgcn_s_setprio(1);
    a0 = __builtin_amdgcn_mfma_f32_32x32x16_bf16(kf[0], qf[0], a0, 0, 0, 0);
    a0 = __builtin_amdgcn_mfma_f32_32x32x16_bf16(kf[1], qf[1], a0, 0, 0, 0);
    a0 = __builtin_amdgcn_mfma_f32_32x32x16_bf16(kf[2], qf[2], a0, 0, 0, 0);
    a0 = __builtin_amdgcn_mfma_f32_32x32x16_bf16(kf[3], qf[3], a0, 0, 0, 0);
    __builtin_amdgcn_s_setprio(0);

    // causal mask: only the diagonal sub-tile
    if (diag) {
        #pragma unroll
        for (int r = 0; r < 16; ++r) {
            int kvl = (r&3) + 8*(r>>2) + 4*hi;
            if (kvl > l31) a0[r] = -1e30f;
        }
    }

    // row max: pairwise tree + cross-half swap
    float x0 = fmaxf(a0[0], a0[1]),   x1 = fmaxf(a0[2], a0[3]);
    float x2 = fmaxf(a0[4], a0[5]),   x3 = fmaxf(a0[6], a0[7]);
    float x4 = fmaxf(a0[8], a0[9]),   x5 = fmaxf(a0[10], a0[11]);
    float x6 = fmaxf(a0[12], a0[13]), x7 = fmaxf(a0[14], a0[15]);
    float y0 = fmaxf(x0, x1), y1 = fmaxf(x2, x3), y2 = fmaxf(x4, x5), y3 = fmaxf(x6, x7);
    float pm = fmaxf(fmaxf(y0, y1), fmaxf(y2, y3));
    pm = xhalf_max(pm);

    // defer-max (T13)
    if (!__all(pm - m_ <= 8.0f)) {
        float mn = fmaxf(m_, pm);
        float alpha = fexp2(m_ - mn);
        l_ *= alpha;
        m_ = mn;
        #pragma unroll
        for (int r = 0; r < 16; ++r) {
            int row = (r&3) + 8*(r>>2) + 4*hi;
            float ar = __shfl(alpha, row);
            o0[r] *= ar;
            o1[r] *= ar;
        }
    }

    // P = exp2(s - m); row sum via pairwise tree + cross-half swap
    #pragma unroll
    for (int r = 0; r < 16; ++r)
        a0[r] = fexp2(a0[r] - m_);
    float s0 = a0[0]+a0[1],  s1 = a0[2]+a0[3],  s2 = a0[4]+a0[5],   s3 = a0[6]+a0[7];
    float s4 = a0[8]+a0[9],  s5 = a0[10]+a0[11], s6 = a0[12]+a0[13], s7 = a0[14]+a0[15];
    float u0 = s0+s1, u1 = s2+s3, u2 = s4+s5, u3 = s6+s7;
    float rs = (u0+u1) + (u2+u3);
    rs = xhalf_sum(rs);
    l_ += rs;

    // pack P to bf16 pairs
    unsigned pk_[8];
    #pragma unroll
    for (int jj = 0; jj < 8; ++jj)
        pk_[jj] = cvtpk_bf16(a0[2*jj], a0[2*jj+1]);

    // PV: A-frag redistribution via permlane32_swap
    #pragma unroll
    for (int kb = 0; kb < 2; ++kb) {
        unsigned fx = pk_[4*kb+0], fz = pk_[4*kb+2];
        unsigned fy = pk_[4*kb+1], fw = pk_[4*kb+3];
        plswap(fx, fz);
        plswap(fy, fw);
        u32x4 wv;
        wv.x = fx; wv.y = fy; wv.z = fz; wv.w = fw;
        short8 pfrag = __builtin_bit_cast(short8, wv);
        __builtin_amdgcn_s_setprio(1);
        o0 = __builtin_amdgcn_mfma_f32_32x32x16_bf16(pfrag, vlo[kb], o0, 0, 0, 0);
        o1 = __builtin_amdgcn_mfma_f32_32x32x16_bf16(pfrag, vhi[kb], o1, 0, 0, 0);
        __builtin_amdgcn_s_setprio(0);
    }
}

__global__ __launch_bounds__(128, 2) void flash_attn(
    const unsigned short* __restrict__ q,
    const unsigned short* __restrict__ k,
    const unsigned short* __restrict__ vt,
    unsigned short* __restrict__ y)
{
    // K tile [64 kv][64 d], V tile [64 d][64 kv], both 16B-slot XOR-swizzled
    __shared__ __align__(16) unsigned short Klds[2][4096];
    __shared__ __align__(16) unsigned short Vlds[2][4096];

    int tid = threadIdx.x, lane = tid & 63, w = tid >> 6;
    int l31 = lane & 31, hi = lane >> 5, rsw = l31 & 7;
    int bid = blockIdx.x;

    int xcd = bid & 7;
    int r = bid >> 3;                 // 0..63
    int bh = xcd*4 + (r & 3);         // 4 heads per XCD for L2 locality
    int s = 15 - (r >> 2);            // supertile (128 rows), heavy first

    const unsigned short* kp = k  + (size_t)bh*T_*D_;
    const unsigned short* vp = vt + (size_t)bh*D_*T_;

    int rowbase = s*128 + w*64;       // this wave's first q row
    const unsigned short* qp = q + ((size_t)bh*T_ + rowbase) * D_;

    short8 qf0[4], qf1[4];
    #pragma unroll
    for (int dk = 0; dk < 4; ++dk) {
        qf0[dk] = *reinterpret_cast<const short8*>(qp + (size_t)l31*D_        + dk*16 + hi*8);
        qf1[dk] = *reinterpret_cast<const short8*>(qp + (size_t)(32 + l31)*D_ + dk*16 + hi*8);
    }

    f32x16 o00 = {}, o01 = {}, o10 = {}, o11 = {};
    float m0 = -1e30f, l0 = 0.f, m1 = -1e30f, l1 = 0.f;

    int nkv = 2*(s + 1);              // KV tiles of 64
    int lim0 = 4*s + 2*w;             // q-block 0: max global 32-kv sub-tile idx
    int lim1 = lim0 + 1;              // q-block 1

    // ---- staging: 512 chunks of 16B per tensor; chunk c -> LDS linear c*16;
    // source slot pre-permuted (slot ^= row&7) so swizzled reads see row-major data.
    #define STAGE(tt, bufi)                                                          \
    {                                                                                \
        _Pragma("unroll")                                                            \
        for (int j = 0; j < 4; ++j) {                                                \
            int c = tid + j*128;                                                     \
            int row_ = c >> 3;                                                       \
            int slot_ = (c & 7) ^ (row_ & 7);                                        \
            gload16(kp + ((size_t)((tt)*64 + row_))*D_ + slot_*8, &Klds[bufi][c*8]); \
            gload16(vp + (size_t)row_*T_ + (tt)*64 + slot_*8,     &Vlds[bufi][c*8]); \
        }                                                                            \
    }

    STAGE(0, 0);
    __syncthreads();

    for (int t = 0; t < nkv; ++t) {
        int bufi = t & 1;
        if (t + 1 < nkv) STAGE(t + 1, bufi ^ 1);

        const unsigned short* Kl = Klds[bufi];
        const unsigned short* Vl = Vlds[bufi];

        #pragma unroll
        for (int st = 0; st < 2; ++st) {
            int g = 2*t + st;
            if (g <= lim1) {
                // K frags: row = st*32 + l31, slot = (dk*2+hi) ^ (row&7)
                short8 kf[4];
                const unsigned short* kr = Kl + (st*32 + l31)*64;
                #pragma unroll
                for (int dk = 0; dk < 4; ++dk)
                    kf[dk] = *reinterpret_cast<const short8*>(kr + (((dk<<1)|hi) ^ rsw)*8);
                // V frags: d rows l31 / 32+l31, slot = (st*4+kb*2+hi) ^ (d&7)
                short8 vlo[2], vhi[2];
                const unsigned short* vr0 = Vl + l31*64;
                const unsigned short* vr1 = Vl + (32 + l31)*64;
                #pragma unroll
                for (int kb = 0; kb < 2; ++kb) {
                    int sl = (((st<<2) | (kb<<1) | hi) ^ rsw) * 8;
                    vlo[kb] = *reinterpret_cast<const short8*>(vr0 + sl);
                    vhi[kb] = *reinterpret_cast<const short8*>(vr1 + sl);
                }
                if (g <= lim0)
                    attn_subtile(kf, qf0, vlo, vhi, g == lim0, l31, hi, o00, o01, m0, l0);
                attn_subtile(kf, qf1, vlo, vhi, g == lim1, l31, hi, o10, o11, m1, l1);
            }
        }
        __syncthreads();
    }

    // ---- epilogue: normalize + write, per q-block (verified R2 pattern) ----
    int b = bh >> 4, h = bh & 15;
    float inv0 = 1.0f / l0;
    float inv1 = 1.0f / l1;
    #pragma unroll
    for (int rr = 0; rr < 16; ++rr) {
        int row = (rr&3) + 8*(rr>>2) + 4*hi;
        float i0 = __shfl(inv0, row);
        float i1 = __shfl(inv1, row);
        int t0r = rowbase + row;
        int t1r = rowbase + 32 + row;
        size_t base0 = ((size_t)(b*T_ + t0r))*C_ + h*64;
        size_t base1 = ((size_t)(b*T_ + t1r))*C_ + h*64;
        y[base0 + l31]      = f2bf(o00[rr] * i0);
        y[base0 + 32 + l31] = f2bf(o01[rr] * i0);
        y[base1 + l31]      = f2bf(o10[rr] * i1);
        y[base1 + 32 + l31] = f2bf(o11[rr] * i1);
    }
    #undef STAGE
}

extern "C" void kernel_launch(void* const* d_in, const int* in_sizes, int n_in,
                              void* d_out, int out_size, void* d_ws, size_t ws_size,
                              hipStream_t stream) {
    const float* x  = (const float*)d_in[0];
    const float* Wk = (const float*)d_in[1];
    const float* bk = (const float*)d_in[2];
    const float* Wq = (const float*)d_in[3];
    const float* bq = (const float*)d_in[4];
    const float* Wv = (const float*)d_in[5];
    const float* bv = (const float*)d_in[6];
    const float* Wo = (const float*)d_in[7];
    const float* bo = (const float*)d_in[8];
    float* out = (float*)d_out;

    char* ws = (char*)d_ws;
    unsigned short* xb  = (unsigned short*)(ws);                    // 8MB
    unsigned short* wkb = (unsigned short*)(ws + ((size_t)8  << 20));
    unsigned short* wqb = (unsigned short*)(ws + ((size_t)10 << 20));
    unsigned short* wvb = (unsigned short*)(ws + ((size_t)12 << 20));
    unsigned short* wob = (unsigned short*)(ws + ((size_t)14 << 20));
    unsigned short* qb  = (unsigned short*)(ws + ((size_t)16 << 20)); // [B,H,T,D]
    unsigned short* kb  = (unsigned short*)(ws + ((size_t)24 << 20)); // [B,H,T,D]
    unsigned short* vtb = (unsigned short*)(ws + ((size_t)32 << 20)); // [B,H,D,T]
    unsigned short* yb  = (unsigned short*)(ws + ((size_t)40 << 20)); // [B*T,C]

    const int nx = B_*T_*C_;   // 4M
    const int nw = C_*C_;      // 1M

    cvt_bf16<<<dim3(nx/4/256), dim3(256), 0, stream>>>(x, xb, nx);
    cvt_bf16_w4<<<dim3(nw/4/256, 4), dim3(256), 0, stream>>>(
        Wk, Wq, Wv, Wo, wkb, wqb, wvb, wob, nw);

    gemm_qkv<<<dim3(768), dim3(256), 0, stream>>>(xb, wkb, wqb, wvb, bk, bq, bv, kb, qb, vtb);

    flash_attn<<<dim3(512), dim3(128), 0, stream>>>(qb, kb, vtb, yb);

    gemm_out<<<dim3(256), dim3(256), 0, stream>>>(yb, wob, bo, out);
}

// Round 9
// 116.511 us; speedup vs baseline: 1.2544x; 1.2471x over previous
//
#include <hip/hip_runtime.h>
#include <hip/hip_bf16.h>
#include <stdint.h>
#include <stddef.h>

#define B_ 2
#define T_ 2048
#define C_ 1024
#define H_ 16
#define D_ 64
#define M_ (B_*T_)   // 4096

typedef __attribute__((ext_vector_type(8))) short short8;
typedef __attribute__((ext_vector_type(4))) float f32x4;
typedef __attribute__((ext_vector_type(16))) float f32x16;
typedef __attribute__((ext_vector_type(4))) unsigned int u32x4;

__device__ __forceinline__ unsigned short f2bf(float f) {
    unsigned u = __float_as_uint(f);
    unsigned r = 0x7FFFu + ((u >> 16) & 1u);
    return (unsigned short)((u + r) >> 16);
}

__device__ __forceinline__ unsigned cvtpk_bf16(float lo, float hi) {
    unsigned r;
    asm("v_cvt_pk_bf16_f32 %0, %1, %2" : "=v"(r) : "v"(lo), "v"(hi));
    return r;
}

// guaranteed single-instruction 2^x
__device__ __forceinline__ float fexp2(float x) {
    float r;
    asm("v_exp_f32 %0, %1" : "=v"(r) : "v"(x));
    return r;
}

// v_permlane32_swap_b32: a = [a_lo | b_lo], b = [a_hi | b_hi]
__device__ __forceinline__ void plswap(unsigned &a, unsigned &b) {
    asm("v_permlane32_swap_b32 %0, %1" : "+v"(a), "+v"(b));
}

__device__ __forceinline__ float xhalf_max(float v) {
    float a = v, b = v;
    asm("" : "+v"(b));
    asm("v_permlane32_swap_b32 %0, %1" : "+v"(a), "+v"(b));
    return fmaxf(a, b);
}
__device__ __forceinline__ float xhalf_sum(float v) {
    float a = v, b = v;
    asm("" : "+v"(b));
    asm("v_permlane32_swap_b32 %0, %1" : "+v"(a), "+v"(b));
    return a + b;
}

__device__ __forceinline__ void gload16(const void* g, void* l) {
    __builtin_amdgcn_global_load_lds(
        (__attribute__((address_space(1))) void*)g,
        (__attribute__((address_space(3))) void*)l,
        16, 0, 0);
}

// ---------------- fp32 -> bf16 conversion ----------------
__global__ void cvt_bf16(const float* __restrict__ in,
                         unsigned short* __restrict__ out, int n) {
    int idx = (blockIdx.x * blockDim.x + threadIdx.x) * 4;
    if (idx >= n) return;
    float4 v = *reinterpret_cast<const float4*>(in + idx);
    ushort4 o;
    o.x = f2bf(v.x); o.y = f2bf(v.y); o.z = f2bf(v.z); o.w = f2bf(v.w);
    *reinterpret_cast<ushort4*>(out + idx) = o;
}

__global__ void cvt_bf16_w4(const float* __restrict__ a, const float* __restrict__ b,
                            const float* __restrict__ c, const float* __restrict__ d,
                            unsigned short* __restrict__ oa, unsigned short* __restrict__ ob,
                            unsigned short* __restrict__ oc, unsigned short* __restrict__ od,
                            int n) {
    int idx = (blockIdx.x * blockDim.x + threadIdx.x) * 4;
    if (idx >= n) return;
    const float* in = (blockIdx.y == 0) ? a : (blockIdx.y == 1) ? b : (blockIdx.y == 2) ? c : d;
    unsigned short* out = (blockIdx.y == 0) ? oa : (blockIdx.y == 1) ? ob : (blockIdx.y == 2) ? oc : od;
    float4 v = *reinterpret_cast<const float4*>(in + idx);
    ushort4 o;
    o.x = f2bf(v.x); o.y = f2bf(v.y); o.z = f2bf(v.z); o.w = f2bf(v.w);
    *reinterpret_cast<ushort4*>(out + idx) = o;
}

// ---------------- fused QKV projection GEMM ----------------
// which 0 -> K [B,H,T,D], which 1 -> Q*scale [B,H,T,D], which 2 -> V^T [B,H,D,T]
__global__ __launch_bounds__(256) void gemm_qkv(
    const unsigned short* __restrict__ A,
    const unsigned short* __restrict__ W0,
    const unsigned short* __restrict__ W1,
    const unsigned short* __restrict__ W2,
    const float* __restrict__ b0,
    const float* __restrict__ b1,
    const float* __restrict__ b2,
    unsigned short* __restrict__ o0,   // k
    unsigned short* __restrict__ o1,   // q (pre-scaled by LOG2E/32)
    unsigned short* __restrict__ o2)   // vt
{
    __shared__ unsigned short As[128*32];
    __shared__ unsigned short Bs[128*32];
    int which = blockIdx.x >> 8;
    int bx = blockIdx.x & 255;
    int bm = bx >> 3, bn = bx & 7;
    const unsigned short* W = (which==0) ? W0 : ((which==1) ? W1 : W2);
    const float* bias = (which==0) ? b0 : ((which==1) ? b1 : b2);

    int tid = threadIdx.x;
    int lane = tid & 63;
    int fr = lane & 15, fq = lane >> 4;
    int wid = tid >> 6;
    int wr = wid >> 1, wc = wid & 1;

    int srow = tid >> 2;            // 0..63
    int scol = (tid & 3) << 3;      // 0,8,16,24
    const unsigned short* Ab = A + (size_t)(bm*128 + srow) * C_ + scol;
    const unsigned short* Wb = W + (size_t)(bn*128 + srow) * C_ + scol;

    f32x4 acc[4][4] = {};

    for (int kt = 0; kt < C_/32; ++kt) {
        int ko = kt*32;
        gload16(Ab + ko,            &As[tid*8]);
        gload16(Ab + 64*C_ + ko,    &As[2048 + tid*8]);
        gload16(Wb + ko,            &Bs[tid*8]);
        gload16(Wb + 64*C_ + ko,    &Bs[2048 + tid*8]);
        __syncthreads();
        short8 af[4], bfr[4];
        #pragma unroll
        for (int i = 0; i < 4; ++i) {
            af[i]  = *reinterpret_cast<const short8*>(&As[(wr*64 + i*16 + fr)*32 + fq*8]);
            bfr[i] = *reinterpret_cast<const short8*>(&Bs[(wc*64 + i*16 + fr)*32 + fq*8]);
        }
        #pragma unroll
        for (int i = 0; i < 4; ++i)
            #pragma unroll
            for (int j = 0; j < 4; ++j)
                acc[i][j] = __builtin_amdgcn_mfma_f32_16x16x32_bf16(af[i], bfr[j], acc[i][j], 0, 0, 0);
        __syncthreads();
    }

    // Q: fold 1/sqrt(C)=1/32 AND log2(e) so QK^T lands in log2 domain
    float sc = (which == 1) ? 0.045084220f : 1.0f;
    int mbase = bm*128 + wr*64;
    int nbase = bn*128 + wc*64;
    #pragma unroll
    for (int j = 0; j < 4; ++j) {
        int col = nbase + j*16 + fr;
        float bv = bias[col];
        int h = col >> 6, d = col & 63;
        #pragma unroll
        for (int i = 0; i < 4; ++i) {
            int r0 = mbase + i*16 + fq*4;
            #pragma unroll
            for (int r = 0; r < 4; ++r) {
                float v = (acc[i][j][r] + bv) * sc;
                int m = r0 + r;
                int b = m >> 11, t = m & (T_-1);
                unsigned short hv = f2bf(v);
                if (which == 2)
                    o2[((size_t)(b*H_ + h)*D_ + d)*T_ + t] = hv;
                else {
                    unsigned short* o = (which==0) ? o0 : o1;
                    o[((size_t)(b*H_ + h)*T_ + t)*D_ + d] = hv;
                }
            }
        }
    }
}

// ---------------- output projection GEMM ----------------
__global__ __launch_bounds__(256) void gemm_out(
    const unsigned short* __restrict__ A,   // y bf16 [M_][C_]
    const unsigned short* __restrict__ W,   // Wo bf16 [C_][C_]
    const float* __restrict__ bias,
    float* __restrict__ out)
{
    __shared__ unsigned short As[128*32];
    __shared__ unsigned short Bs[128*32];
    int bx = blockIdx.x;
    int bm = bx >> 3, bn = bx & 7;

    int tid = threadIdx.x;
    int lane = tid & 63;
    int fr = lane & 15, fq = lane >> 4;
    int wid = tid >> 6;
    int wr = wid >> 1, wc = wid & 1;

    int srow = tid >> 2;
    int scol = (tid & 3) << 3;
    const unsigned short* Ab = A + (size_t)(bm*128 + srow) * C_ + scol;
    const unsigned short* Wb = W + (size_t)(bn*128 + srow) * C_ + scol;

    f32x4 acc[4][4] = {};

    for (int kt = 0; kt < C_/32; ++kt) {
        int ko = kt*32;
        gload16(Ab + ko,            &As[tid*8]);
        gload16(Ab + 64*C_ + ko,    &As[2048 + tid*8]);
        gload16(Wb + ko,            &Bs[tid*8]);
        gload16(Wb + 64*C_ + ko,    &Bs[2048 + tid*8]);
        __syncthreads();
        short8 af[4], bfr[4];
        #pragma unroll
        for (int i = 0; i < 4; ++i) {
            af[i]  = *reinterpret_cast<const short8*>(&As[(wr*64 + i*16 + fr)*32 + fq*8]);
            bfr[i] = *reinterpret_cast<const short8*>(&Bs[(wc*64 + i*16 + fr)*32 + fq*8]);
        }
        #pragma unroll
        for (int i = 0; i < 4; ++i)
            #pragma unroll
            for (int j = 0; j < 4; ++j)
                acc[i][j] = __builtin_amdgcn_mfma_f32_16x16x32_bf16(af[i], bfr[j], acc[i][j], 0, 0, 0);
        __syncthreads();
    }

    int mbase = bm*128 + wr*64;
    int nbase = bn*128 + wc*64;
    #pragma unroll
    for (int j = 0; j < 4; ++j) {
        int col = nbase + j*16 + fr;
        float bv = bias[col];
        #pragma unroll
        for (int i = 0; i < 4; ++i) {
            int r0 = mbase + i*16 + fq*4;
            #pragma unroll
            for (int r = 0; r < 4; ++r)
                out[(size_t)(r0 + r)*C_ + col] = acc[i][j][r] + bv;
        }
    }
}

// ---------------- flash attention: staged + in-block 2-way KV split ----------------
// Block = 4 waves / 256 thr. Waves {0,1}: kv tiles [0,S+1); waves {2,3}: [S+1,2S+2).
// Wave pair (w, w+2) owns the same 64 q-rows (2 chains of 32). LDS merge at end.
__device__ __forceinline__ void attn_subtile(
    const short8 (&kf)[4], const short8 (&qf)[4],
    const short8 (&vlo)[2], const short8 (&vhi)[2],
    bool diag, int l31, int hi,
    f32x16& o0, f32x16& o1, float& m_, float& l_)
{
    // QK^T (swapped: A=K, B=Q): a0 col = q row (l31), row = kv_local
    f32x16 a0 = {};
    __builtin_amdgcn_s_setprio(1);
    a0 = __builtin_amdgcn_mfma_f32_32x32x16_bf16(kf[0], qf[0], a0, 0, 0, 0);
    a0 = __builtin_amdgcn_mfma_f32_32x32x16_bf16(kf[1], qf[1], a0, 0, 0, 0);
    a0 = __builtin_amdgcn_mfma_f32_32x32x16_bf16(kf[2], qf[2], a0, 0, 0, 0);
    a0 = __builtin_amdgcn_mfma_f32_32x32x16_bf16(kf[3], qf[3], a0, 0, 0, 0);
    __builtin_amdgcn_s_setprio(0);

    // causal mask: only the diagonal sub-tile
    if (diag) {
        #pragma unroll
        for (int r = 0; r < 16; ++r) {
            int kvl = (r&3) + 8*(r>>2) + 4*hi;
            if (kvl > l31) a0[r] = -1e30f;
        }
    }

    // row max: pairwise tree + cross-half swap
    float x0 = fmaxf(a0[0], a0[1]),   x1 = fmaxf(a0[2], a0[3]);
    float x2 = fmaxf(a0[4], a0[5]),   x3 = fmaxf(a0[6], a0[7]);
    float x4 = fmaxf(a0[8], a0[9]),   x5 = fmaxf(a0[10], a0[11]);
    float x6 = fmaxf(a0[12], a0[13]), x7 = fmaxf(a0[14], a0[15]);
    float y0 = fmaxf(x0, x1), y1 = fmaxf(x2, x3), y2 = fmaxf(x4, x5), y3 = fmaxf(x6, x7);
    float pm = fmaxf(fmaxf(y0, y1), fmaxf(y2, y3));
    pm = xhalf_max(pm);

    // defer-max (T13)
    if (!__all(pm - m_ <= 8.0f)) {
        float mn = fmaxf(m_, pm);
        float alpha = fexp2(m_ - mn);
        l_ *= alpha;
        m_ = mn;
        #pragma unroll
        for (int r = 0; r < 16; ++r) {
            int row = (r&3) + 8*(r>>2) + 4*hi;
            float ar = __shfl(alpha, row);
            o0[r] *= ar;
            o1[r] *= ar;
        }
    }

    // P = exp2(s - m); row sum via pairwise tree + cross-half swap
    #pragma unroll
    for (int r = 0; r < 16; ++r)
        a0[r] = fexp2(a0[r] - m_);
    float s0 = a0[0]+a0[1],  s1 = a0[2]+a0[3],  s2 = a0[4]+a0[5],   s3 = a0[6]+a0[7];
    float s4 = a0[8]+a0[9],  s5 = a0[10]+a0[11], s6 = a0[12]+a0[13], s7 = a0[14]+a0[15];
    float u0 = s0+s1, u1 = s2+s3, u2 = s4+s5, u3 = s6+s7;
    float rs = (u0+u1) + (u2+u3);
    rs = xhalf_sum(rs);
    l_ += rs;

    // pack P to bf16 pairs
    unsigned pk_[8];
    #pragma unroll
    for (int jj = 0; jj < 8; ++jj)
        pk_[jj] = cvtpk_bf16(a0[2*jj], a0[2*jj+1]);

    // PV: A-frag redistribution via permlane32_swap
    #pragma unroll
    for (int kb = 0; kb < 2; ++kb) {
        unsigned fx = pk_[4*kb+0], fz = pk_[4*kb+2];
        unsigned fy = pk_[4*kb+1], fw = pk_[4*kb+3];
        plswap(fx, fz);
        plswap(fy, fw);
        u32x4 wv;
        wv.x = fx; wv.y = fy; wv.z = fz; wv.w = fw;
        short8 pfrag = __builtin_bit_cast(short8, wv);
        __builtin_amdgcn_s_setprio(1);
        o0 = __builtin_amdgcn_mfma_f32_32x32x16_bf16(pfrag, vlo[kb], o0, 0, 0, 0);
        o1 = __builtin_amdgcn_mfma_f32_32x32x16_bf16(pfrag, vhi[kb], o1, 0, 0, 0);
        __builtin_amdgcn_s_setprio(0);
    }
}

__global__ __launch_bounds__(256, 2) void flash_attn(
    const unsigned short* __restrict__ q,
    const unsigned short* __restrict__ k,
    const unsigned short* __restrict__ vt,
    unsigned short* __restrict__ y)
{
    // staging: [buf][tensor][4096 shorts]; tensors: 0=K_lo 1=K_hi 2=V_lo 3=V_hi (64 KB)
    __shared__ __align__(16) unsigned short ST[2][4][4096];
    // merge overlay (used only after the final compute barrier):
    float* oP  = reinterpret_cast<float*>(&ST[0][0][0]);   // [4 sets][32 rows][68]
    float* mlP = oP + 4*32*68;                             // m: [set*32+l31], l: +128

    int tid = threadIdx.x, lane = tid & 63, w = tid >> 6;
    int l31 = lane & 31, hi = lane >> 5, rsw = l31 & 7;
    int role = w >> 1, pair = w & 1;
    int bid = blockIdx.x;

    int xcd = bid & 7;
    int r = bid >> 3;                 // 0..63
    int bh = xcd*4 + (r & 3);         // 4 heads per XCD
    int S = 15 - (r >> 2);            // supertile (128 q-rows), heavy first

    const unsigned short* kp = k  + (size_t)bh*T_*D_;
    const unsigned short* vp = vt + (size_t)bh*D_*T_;

    int rowbase = S*128 + pair*64;    // this wave-pair's first q row
    const unsigned short* qp = q + ((size_t)bh*T_ + rowbase) * D_;

    short8 qf0[4], qf1[4];
    #pragma unroll
    for (int dk = 0; dk < 4; ++dk) {
        qf0[dk] = *reinterpret_cast<const short8*>(qp + (size_t)l31*D_        + dk*16 + hi*8);
        qf1[dk] = *reinterpret_cast<const short8*>(qp + (size_t)(32 + l31)*D_ + dk*16 + hi*8);
    }

    f32x16 o00 = {}, o01 = {}, o10 = {}, o11 = {};
    float m0 = -1e30f, l0 = 0.f, m1 = -1e30f, l1 = 0.f;

    int lim0 = 4*S + 2*pair;          // chain0 diag sub-tile (global g)
    int lim1 = lim0 + 1;              // chain1
    int niter = S + 1;                // tiles per stream

    // stage iteration ii: low tile = ii, high tile = S+1+ii (512 chunks/tensor)
    #define STAGE(ii, bufi)                                                            \
    {                                                                                  \
        _Pragma("unroll")                                                              \
        for (int jj = 0; jj < 2; ++jj) {                                               \
            int c2 = tid + jj*256;                                                     \
            int row_ = c2 >> 3;                                                        \
            int slot_ = (c2 & 7) ^ (row_ & 7);                                         \
            int tl_ = (ii), th_ = S + 1 + (ii);                                        \
            gload16(kp + ((size_t)(tl_*64 + row_))*D_ + slot_*8, &ST[bufi][0][c2*8]);  \
            gload16(kp + ((size_t)(th_*64 + row_))*D_ + slot_*8, &ST[bufi][1][c2*8]);  \
            gload16(vp + (size_t)row_*T_ + tl_*64 + slot_*8,     &ST[bufi][2][c2*8]);  \
            gload16(vp + (size_t)row_*T_ + th_*64 + slot_*8,     &ST[bufi][3][c2*8]);  \
        }                                                                              \
    }

    STAGE(0, 0);
    __syncthreads();

    for (int i = 0; i < niter; ++i) {
        int bufi = i & 1;
        if (i + 1 < niter) STAGE(i + 1, bufi ^ 1);

        const unsigned short* Kl = &ST[bufi][role][0];
        const unsigned short* Vl = &ST[bufi][2 + role][0];
        int t = role ? (S + 1 + i) : i;

        #pragma unroll
        for (int st = 0; st < 2; ++st) {
            int g = 2*t + st;
            if (g <= lim1) {
                short8 kf[4];
                const unsigned short* kr = Kl + (st*32 + l31)*64;
                #pragma unroll
                for (int dk = 0; dk < 4; ++dk)
                    kf[dk] = *reinterpret_cast<const short8*>(kr + (((dk<<1)|hi) ^ rsw)*8);
                short8 vlo[2], vhi[2];
                const unsigned short* vr0 = Vl + l31*64;
                const unsigned short* vr1 = Vl + (32 + l31)*64;
                #pragma unroll
                for (int kb = 0; kb < 2; ++kb) {
                    int sl = (((st<<2) | (kb<<1) | hi) ^ rsw) * 8;
                    vlo[kb] = *reinterpret_cast<const short8*>(vr0 + sl);
                    vhi[kb] = *reinterpret_cast<const short8*>(vr1 + sl);
                }
                if (g <= lim0)
                    attn_subtile(kf, qf0, vlo, vhi, g == lim0, l31, hi, o00, o01, m0, l0);
                attn_subtile(kf, qf1, vlo, vhi, g == lim1, l31, hi, o10, o11, m1, l1);
            }
        }
        __syncthreads();
    }
    #undef STAGE

    // ---- merge the two KV halves (low waves store; high waves combine + write) ----
    if (!role) {
        int s0 = pair*2, s1 = pair*2 + 1;
        #pragma unroll
        for (int rr = 0; rr < 16; ++rr) {
            int crow = (rr&3) + 8*(rr>>2) + 4*hi;
            oP[(s0*32 + crow)*68 + l31]      = o00[rr];
            oP[(s0*32 + crow)*68 + 32 + l31] = o01[rr];
            oP[(s1*32 + crow)*68 + l31]      = o10[rr];
            oP[(s1*32 + crow)*68 + 32 + l31] = o11[rr];
        }
        if (!hi) {
            mlP[s0*32 + l31]       = m0;
            mlP[128 + s0*32 + l31] = l0;
            mlP[s1*32 + l31]       = m1;
            mlP[128 + s1*32 + l31] = l1;
        }
    }
    __syncthreads();
    if (role) {
        int b = bh >> 4, h = bh & 15;
        #pragma unroll
        for (int qq = 0; qq < 2; ++qq) {
            int set = pair*2 + qq;
            const f32x16& po0 = qq ? o10 : o00;
            const f32x16& po1 = qq ? o11 : o01;
            float m_ = qq ? m1 : m0;
            float l_ = qq ? l1 : l0;

            float mA = mlP[set*32 + l31];
            float lA = mlP[128 + set*32 + l31];
            float mN = fmaxf(mA, m_);
            float aA = fexp2(mA - mN);
            float aB = fexp2(m_ - mN);
            float lN = lA*aA + l_*aB;
            float inv = 1.0f / lN;
            float cA = aA * inv, cB = aB * inv;

            #pragma unroll
            for (int rr = 0; rr < 16; ++rr) {
                int crow = (rr&3) + 8*(rr>>2) + 4*hi;
                float cAr = __shfl(cA, crow);
                float cBr = __shfl(cB, crow);
                float vA0 = oP[(set*32 + crow)*68 + l31];
                float vA1 = oP[(set*32 + crow)*68 + 32 + l31];
                int trow = rowbase + qq*32 + crow;
                size_t base = ((size_t)(b*T_ + trow))*C_ + h*64;
                y[base + l31]      = f2bf(vA0*cAr + po0[rr]*cBr);
                y[base + 32 + l31] = f2bf(vA1*cAr + po1[rr]*cBr);
            }
        }
    }
}

extern "C" void kernel_launch(void* const* d_in, const int* in_sizes, int n_in,
                              void* d_out, int out_size, void* d_ws, size_t ws_size,
                              hipStream_t stream) {
    const float* x  = (const float*)d_in[0];
    const float* Wk = (const float*)d_in[1];
    const float* bk = (const float*)d_in[2];
    const float* Wq = (const float*)d_in[3];
    const float* bq = (const float*)d_in[4];
    const float* Wv = (const float*)d_in[5];
    const float* bv = (const float*)d_in[6];
    const float* Wo = (const float*)d_in[7];
    const float* bo = (const float*)d_in[8];
    float* out = (float*)d_out;

    char* ws = (char*)d_ws;
    unsigned short* xb  = (unsigned short*)(ws);                    // 8MB
    unsigned short* wkb = (unsigned short*)(ws + ((size_t)8  << 20));
    unsigned short* wqb = (unsigned short*)(ws + ((size_t)10 << 20));
    unsigned short* wvb = (unsigned short*)(ws + ((size_t)12 << 20));
    unsigned short* wob = (unsigned short*)(ws + ((size_t)14 << 20));
    unsigned short* qb  = (unsigned short*)(ws + ((size_t)16 << 20)); // [B,H,T,D]
    unsigned short* kb  = (unsigned short*)(ws + ((size_t)24 << 20)); // [B,H,T,D]
    unsigned short* vtb = (unsigned short*)(ws + ((size_t)32 << 20)); // [B,H,D,T]
    unsigned short* yb  = (unsigned short*)(ws + ((size_t)40 << 20)); // [B*T,C]

    const int nx = B_*T_*C_;   // 4M
    const int nw = C_*C_;      // 1M

    cvt_bf16<<<dim3(nx/4/256), dim3(256), 0, stream>>>(x, xb, nx);
    cvt_bf16_w4<<<dim3(nw/4/256, 4), dim3(256), 0, stream>>>(
        Wk, Wq, Wv, Wo, wkb, wqb, wvb, wob, nw);

    gemm_qkv<<<dim3(768), dim3(256), 0, stream>>>(xb, wkb, wqb, wvb, bk, bq, bv, kb, qb, vtb);

    flash_attn<<<dim3(512), dim3(256), 0, stream>>>(qb, kb, vtb, yb);

    gemm_out<<<dim3(256), dim3(256), 0, stream>>>(yb, wob, bo, out);
}